// Round 2
// baseline (650.889 us; speedup 1.0000x reference)
//
#include <hip/hip_runtime.h>
#include <math.h>

#define B_  16
#define Hh  56
#define Ww  56
#define L_  3136
#define C_  192
#define NH  6
#define HD  32
#define BL  50176   // B_*L_

__device__ __forceinline__ float silu_f(float v) { return v / (1.f + expf(-v)); }

// ---------------- LayerNorm: one wave per token ----------------
__global__ __launch_bounds__(256) void k_ln(const float* __restrict__ x,
                                            const float* __restrict__ g,
                                            const float* __restrict__ bt,
                                            float* __restrict__ xn)
{
    int token = blockIdx.x * 4 + (threadIdx.x >> 6);
    int lane  = threadIdx.x & 63;
    const float* xr = x + (size_t)token * C_;
    float v0 = xr[lane], v1 = xr[lane + 64], v2 = xr[lane + 128];
    float s  = v0 + v1 + v2;
    float sq = v0 * v0 + v1 * v1 + v2 * v2;
#pragma unroll
    for (int off = 32; off > 0; off >>= 1) {
        s  += __shfl_xor(s, off);
        sq += __shfl_xor(sq, off);
    }
    float mu  = s * (1.f / C_);
    float var = sq * (1.f / C_) - mu * mu;
    float rs  = rsqrtf(var + 1e-5f);
    float* o = xn + (size_t)token * C_;
    o[lane]       = (v0 - mu) * rs * g[lane]       + bt[lane];
    o[lane + 64]  = (v1 - mu) * rs * g[lane + 64]  + bt[lane + 64];
    o[lane + 128] = (v2 - mu) * rs * g[lane + 128] + bt[lane + 128];
}

// ---------------- Generic tiled fp32 GEMM, M=BL, K=192 ----------------
// MODE 0: N=384 split over two weight mats: [act_w -> silu -> Oa][in_w -> Ob]
// MODE 1: W=qk_w [192,384], elu+1 epilogue, cols<192 -> Oa(q), >=192 -> Ob(k)
// MODE 2: W=out_w [192,192], epilogue + bias + Xres (shortcut) -> Oa
template <int MODE>
__global__ __launch_bounds__(256) void k_gemm(
    const float* __restrict__ A,
    const float* __restrict__ Wa, const float* __restrict__ Wb,
    const float* __restrict__ ba, const float* __restrict__ bb,
    float* __restrict__ Oa, float* __restrict__ Ob,
    const float* __restrict__ Xres)
{
    __shared__ float As[64][33];
    __shared__ __align__(16) float Bs[32][64];
    const int t  = threadIdx.x;
    const int m0 = blockIdx.x * 64;
    const int n0 = blockIdx.y * 64;
    const int tm = t >> 4, tn = t & 15;

    const float* W; int ldw; int wcol;
    if constexpr (MODE == 0) {
        if (n0 < C_) { W = Wa; ldw = C_; wcol = n0; }
        else         { W = Wb; ldw = C_; wcol = n0 - C_; }
    } else if constexpr (MODE == 1) {
        W = Wa; ldw = 2 * C_; wcol = n0;
    } else {
        W = Wa; ldw = C_; wcol = n0;
    }

    float acc[4][4] = {};

    for (int k0 = 0; k0 < C_; k0 += 32) {
#pragma unroll
        for (int i = 0; i < 2; ++i) {
            int f = t + i * 256;
            int r = f >> 3, kq = (f & 7) << 2;
            float4 av = *(const float4*)(A + (size_t)(m0 + r) * C_ + (k0 + kq));
            As[r][kq + 0] = av.x; As[r][kq + 1] = av.y;
            As[r][kq + 2] = av.z; As[r][kq + 3] = av.w;
        }
#pragma unroll
        for (int i = 0; i < 2; ++i) {
            int f = t + i * 256;
            int kk = f >> 4, n4 = (f & 15) << 2;
            *(float4*)&Bs[kk][n4] = *(const float4*)(W + (size_t)(k0 + kk) * ldw + wcol + n4);
        }
        __syncthreads();
#pragma unroll
        for (int kk = 0; kk < 32; ++kk) {
            float a0 = As[tm * 4 + 0][kk];
            float a1 = As[tm * 4 + 1][kk];
            float a2 = As[tm * 4 + 2][kk];
            float a3 = As[tm * 4 + 3][kk];
            float4 bv = *(const float4*)&Bs[kk][tn * 4];
            acc[0][0] += a0 * bv.x; acc[0][1] += a0 * bv.y; acc[0][2] += a0 * bv.z; acc[0][3] += a0 * bv.w;
            acc[1][0] += a1 * bv.x; acc[1][1] += a1 * bv.y; acc[1][2] += a1 * bv.z; acc[1][3] += a1 * bv.w;
            acc[2][0] += a2 * bv.x; acc[2][1] += a2 * bv.y; acc[2][2] += a2 * bv.z; acc[2][3] += a2 * bv.w;
            acc[3][0] += a3 * bv.x; acc[3][1] += a3 * bv.y; acc[3][2] += a3 * bv.z; acc[3][3] += a3 * bv.w;
        }
        __syncthreads();
    }

    int ng = n0 + tn * 4;
#pragma unroll
    for (int i = 0; i < 4; ++i) {
        size_t mrow = (size_t)(m0 + tm * 4 + i);
        float4 r; float* vp = &r.x;
        if constexpr (MODE == 0) {
            if (n0 < C_) {
#pragma unroll
                for (int j = 0; j < 4; ++j) vp[j] = silu_f(acc[i][j] + ba[ng + j]);
                *(float4*)(Oa + mrow * C_ + ng) = r;
            } else {
#pragma unroll
                for (int j = 0; j < 4; ++j) vp[j] = acc[i][j] + bb[ng - C_ + j];
                *(float4*)(Ob + mrow * C_ + (ng - C_)) = r;
            }
        } else if constexpr (MODE == 1) {
#pragma unroll
            for (int j = 0; j < 4; ++j) {
                float z = acc[i][j] + ba[ng + j];
                vp[j] = (z > 0.f) ? (z + 1.f) : expf(z);
            }
            if (n0 < C_) *(float4*)(Oa + mrow * C_ + ng) = r;
            else         *(float4*)(Ob + mrow * C_ + (ng - C_)) = r;
        } else {
#pragma unroll
            for (int j = 0; j < 4; ++j)
                vp[j] = acc[i][j] + ba[ng + j] + Xres[mrow * C_ + ng + j];
            *(float4*)(Oa + mrow * C_ + ng) = r;
        }
    }
}

// ---------------- depthwise 3x3 conv (+optional silu) ----------------
template <bool DO_SILU>
__global__ __launch_bounds__(192) void k_dwconv(const float* __restrict__ in,
                                                const float* __restrict__ w,
                                                const float* __restrict__ bias,
                                                float* __restrict__ out)
{
    int pos = blockIdx.x;
    int c   = threadIdx.x;
    int b   = pos / L_;
    int rem = pos - b * L_;
    int y   = rem / Ww;
    int x   = rem - y * Ww;
    float acc = bias[c];
#pragma unroll
    for (int dy = -1; dy <= 1; ++dy) {
        int yy = y + dy;
        if ((unsigned)yy >= Hh) continue;
#pragma unroll
        for (int dx = -1; dx <= 1; ++dx) {
            int xx = x + dx;
            if ((unsigned)xx >= Ww) continue;
            acc += in[((size_t)(b * L_ + yy * Ww + xx)) * C_ + c] *
                   w[((dy + 1) * 3 + (dx + 1)) * C_ + c];
        }
    }
    if (DO_SILU) acc = silu_f(acc);
    out[(size_t)pos * C_ + c] = acc;
}

// ---------------- kv = k^T v / L and kmean = sum_l k / L ----------------
__global__ __launch_bounds__(256) void k_kv(const float* __restrict__ kbuf,
                                            const float* __restrict__ vbuf,
                                            float* __restrict__ kv,
                                            float* __restrict__ ksum)
{
    __shared__ __align__(16) float Ks[16][32];
    __shared__ __align__(16) float Vs[16][32];
    int bh = blockIdx.x;          // 0..95
    int chunk = blockIdx.y;       // 0..6  (448 rows each)
    int b = bh / NH, h = bh % NH;
    int t = threadIdx.x;
    int l0 = chunk * 448;
    int d  = t >> 3;
    int e0 = (t & 7) << 2;
    float a0 = 0, a1 = 0, a2 = 0, a3 = 0, ks = 0;
    int lr = t & 127;
    int rr = lr >> 3, d4 = (lr & 7) << 2;
    for (int l = l0; l < l0 + 448; l += 16) {
        __syncthreads();
        size_t base = ((size_t)(b * L_ + l + rr)) * C_ + h * HD + d4;
        if (t < 128) *(float4*)&Ks[rr][d4] = *(const float4*)(kbuf + base);
        else         *(float4*)&Vs[rr][d4] = *(const float4*)(vbuf + base);
        __syncthreads();
#pragma unroll
        for (int r = 0; r < 16; ++r) {
            float kd = Ks[r][d];
            float4 vv = *(const float4*)&Vs[r][e0];
            a0 += kd * vv.x; a1 += kd * vv.y; a2 += kd * vv.z; a3 += kd * vv.w;
            if (e0 == 0) ks += kd;
        }
    }
    const float invL = 1.f / (float)L_;
    float* kvp = kv + (size_t)bh * HD * HD + d * HD + e0;
    atomicAdd(kvp + 0, a0 * invL);
    atomicAdd(kvp + 1, a1 * invL);
    atomicAdd(kvp + 2, a2 * invL);
    atomicAdd(kvp + 3, a3 * invL);
    if (e0 == 0) atomicAdd(ksum + bh * HD + d, ks * invL);
}

// ---------------- att = (q@kv)*z + lepe(h), times act_res ----------------
__global__ __launch_bounds__(192) void k_att(const float* __restrict__ q,
                                             const float* __restrict__ kv,
                                             const float* __restrict__ kmean,
                                             const float* __restrict__ hbuf,
                                             const float* __restrict__ act,
                                             const float* __restrict__ lw,
                                             const float* __restrict__ lb,
                                             float* __restrict__ outp)
{
    __shared__ __align__(16) float kvs[NH * HD * HD];  // 24 KB
    __shared__ float kms[C_];
    __shared__ float qs[C_];
    int t   = threadIdx.x;
    int bl0 = blockIdx.x * 8;
    int b   = bl0 / L_;
    const float* kvg = kv + (size_t)b * NH * HD * HD;
#pragma unroll
    for (int i = 0; i < 8; ++i) {
        int f = i * 192 + t;
        *(float4*)&kvs[f * 4] = *(const float4*)(kvg + f * 4);
    }
    kms[t] = kmean[b * C_ + t];
    int h = t >> 5, e = t & 31;
    float wl[9];
    float lbias = lb[t];
#pragma unroll
    for (int j = 0; j < 9; ++j) wl[j] = lw[j * C_ + t];

    for (int it = 0; it < 8; ++it) {
        int bl = bl0 + it;
        __syncthreads();
        qs[t] = q[(size_t)bl * C_ + t];
        __syncthreads();
        float qdot = 0.f;
#pragma unroll
        for (int d0 = 0; d0 < HD; ++d0) qdot += qs[h * HD + d0] * kms[h * HD + d0];
        float z = 1.f / (qdot + 1e-6f);
        float av = 0.f;
        const float* kvh = &kvs[h * HD * HD];
#pragma unroll
        for (int d0 = 0; d0 < HD; ++d0) av += qs[h * HD + d0] * kvh[d0 * HD + e];
        av *= z;
        // lepe dwconv
        int rem = bl - b * L_;
        int y = rem / Ww, x = rem - y * Ww;
        float lp = lbias;
#pragma unroll
        for (int dy = -1; dy <= 1; ++dy) {
            int yy = y + dy;
            if ((unsigned)yy >= Hh) continue;
#pragma unroll
            for (int dx = -1; dx <= 1; ++dx) {
                int xx = x + dx;
                if ((unsigned)xx >= Ww) continue;
                lp += hbuf[((size_t)(b * L_ + yy * Ww + xx)) * C_ + t] *
                      wl[(dy + 1) * 3 + (dx + 1)];
            }
        }
        outp[(size_t)bl * C_ + t] = (av + lp) * act[(size_t)bl * C_ + t];
    }
}

extern "C" void kernel_launch(void* const* d_in, const int* in_sizes, int n_in,
                              void* d_out, int out_size, void* d_ws, size_t ws_size,
                              hipStream_t stream)
{
    const float* x      = (const float*)d_in[0];
    const float* norm_g = (const float*)d_in[1];
    const float* norm_b = (const float*)d_in[2];
    const float* in_w   = (const float*)d_in[3];
    const float* in_b   = (const float*)d_in[4];
    const float* act_w  = (const float*)d_in[5];
    const float* act_b  = (const float*)d_in[6];
    const float* dwc_w  = (const float*)d_in[7];
    const float* dwc_b  = (const float*)d_in[8];
    const float* qk_w   = (const float*)d_in[9];
    const float* qk_b   = (const float*)d_in[10];
    const float* lepe_w = (const float*)d_in[11];
    const float* lepe_b = (const float*)d_in[12];
    const float* out_w  = (const float*)d_in[13];
    const float* out_b  = (const float*)d_in[14];
    float* out = (float*)d_out;
    float* ws  = (float*)d_ws;

    const size_t SZ = (size_t)BL * C_;
    float* buf0 = ws;            // xn, later q
    float* buf1 = ws + SZ;       // act_res
    float* buf2 = ws + 2 * SZ;   // h0, later k, later attres
    float* buf3 = ws + 3 * SZ;   // h
    float* kvb  = ws + 4 * SZ;   // 96*1024
    float* kmean = kvb + 96 * HD * HD;

    // 1. LayerNorm
    k_ln<<<BL / 4, 256, 0, stream>>>(x, norm_g, norm_b, buf0);
    // 2. act_res = silu(xn@act_w+b), h0 = xn@in_w+b
    dim3 g1(BL / 64, 6);
    k_gemm<0><<<g1, 256, 0, stream>>>(buf0, act_w, in_w, act_b, in_b, buf1, buf2, nullptr);
    // 3. h = silu(dwconv(h0))
    k_dwconv<true><<<BL, 192, 0, stream>>>(buf2, dwc_w, dwc_b, buf3);
    // 4. qk = h@qk_w + b, elu+1 -> q(buf0), k(buf2)
    k_gemm<1><<<g1, 256, 0, stream>>>(buf3, qk_w, nullptr, qk_b, nullptr, buf0, buf2, nullptr);
    // 5. zero kv + kmean
    hipMemsetAsync(kvb, 0, (size_t)(96 * HD * HD + 96 * HD) * sizeof(float), stream);
    // 6. kv = k^T v / L, kmean
    dim3 g2(96, 7);
    k_kv<<<g2, 256, 0, stream>>>(buf2, buf3, kvb, kmean);
    // 7. attres = (q@kv*z + lepe(h)) * act_res -> buf2
    k_att<<<BL / 8, 192, 0, stream>>>(buf0, kvb, kmean, buf3, buf1, lepe_w, lepe_b, buf2);
    // 8. out = attres@out_w + out_b + x
    dim3 g3(BL / 64, 3);
    k_gemm<2><<<g3, 256, 0, stream>>>(buf2, out_w, nullptr, out_b, nullptr, out, nullptr, x);
}

// Round 4
// 455.384 us; speedup vs baseline: 1.4293x; 1.4293x over previous
//
#include <hip/hip_runtime.h>
#include <hip/hip_bf16.h>
#include <math.h>

#define B_  16
#define Hh  56
#define Ww  56
#define L_  3136
#define C_  192
#define NH  6
#define HD  32
#define BL  50176   // B_*L_

typedef short bf16x8 __attribute__((ext_vector_type(8)));
typedef float f32x4  __attribute__((ext_vector_type(4)));

__device__ __forceinline__ float silu_f(float v) { return v / (1.f + expf(-v)); }
__device__ __forceinline__ float bf2f(ushort u) { union { uint i; float f; } v; v.i = (uint)u << 16; return v.f; }
__device__ __forceinline__ ushort f2bf(float f) { __hip_bfloat16 h = __float2bfloat16(f); return *reinterpret_cast<ushort*>(&h); }

// ---------------- weight prep: transpose + bf16 cast ----------------
__global__ __launch_bounds__(192) void k_prep(
    const float* __restrict__ act_w, const float* __restrict__ in_w,
    const float* __restrict__ qk_w,  const float* __restrict__ out_w,
    const float* __restrict__ act_b, const float* __restrict__ in_b,
    ushort* __restrict__ wcat, ushort* __restrict__ qkt,
    ushort* __restrict__ outt, float* __restrict__ cb0)
{
    int n = blockIdx.x, k = threadIdx.x;
    if (n < 384) {
        float v = (n < 192) ? act_w[k * 192 + n] : in_w[k * 192 + (n - 192)];
        wcat[n * 192 + k] = f2bf(v);
        if (k == 0) cb0[n] = (n < 192) ? act_b[n] : in_b[n - 192];
    } else if (n < 768) {
        int nn = n - 384;
        qkt[nn * 192 + k] = f2bf(qk_w[k * 384 + nn]);
    } else {
        int nn = n - 768;
        outt[nn * 192 + k] = f2bf(out_w[k * 192 + nn]);
    }
}

// ---------------- LayerNorm -> bf16 ----------------
__global__ __launch_bounds__(256) void k_ln(const float* __restrict__ x,
                                            const float* __restrict__ g,
                                            const float* __restrict__ bt,
                                            ushort* __restrict__ xn)
{
    int token = blockIdx.x * 4 + (threadIdx.x >> 6);
    int lane  = threadIdx.x & 63;
    const float* xr = x + (size_t)token * C_;
    float v0 = xr[lane], v1 = xr[lane + 64], v2 = xr[lane + 128];
    float s  = v0 + v1 + v2;
    float sq = v0 * v0 + v1 * v1 + v2 * v2;
#pragma unroll
    for (int off = 32; off > 0; off >>= 1) {
        s  += __shfl_xor(s, off);
        sq += __shfl_xor(sq, off);
    }
    float mu  = s * (1.f / C_);
    float var = sq * (1.f / C_) - mu * mu;
    float rs  = rsqrtf(var + 1e-5f);
    ushort* o = xn + (size_t)token * C_;
    o[lane]       = f2bf((v0 - mu) * rs * g[lane]       + bt[lane]);
    o[lane + 64]  = f2bf((v1 - mu) * rs * g[lane + 64]  + bt[lane + 64]);
    o[lane + 128] = f2bf((v2 - mu) * rs * g[lane + 128] + bt[lane + 128]);
}

// ---------------- MFMA GEMM: [BL,192] x Wt[NT,192]^T, 128x64 tile ----------------
template <int MODE>
__global__ __launch_bounds__(256) void k_mm(
    const ushort* __restrict__ A, const ushort* __restrict__ Wt,
    const float* __restrict__ cb,
    ushort* __restrict__ Oa, ushort* __restrict__ Ob,
    const float* __restrict__ Xres, float* __restrict__ Ofp)
{
    __shared__ __align__(16) ushort As[128 * 40];
    __shared__ __align__(16) ushort Bs[64 * 40];
    const int t = threadIdx.x;
    const int m0 = blockIdx.x * 128, n0 = blockIdx.y * 64;
    const int l = t & 63, w = t >> 6;
    const int wm = w & 1, wn = w >> 1;
    const int lr = l & 15, lk = l >> 4;
    const int ar = t >> 1, ah = t & 1;
    const int bn = t >> 2, bq = t & 3;

    f32x4 acc[4][2] = {};

    for (int k0 = 0; k0 < 192; k0 += 32) {
        if (k0) __syncthreads();
        const ushort* as = A + (size_t)(m0 + ar) * 192 + k0 + ah * 16;
        bf16x8 av0 = *(const bf16x8*)as;
        bf16x8 av1 = *(const bf16x8*)(as + 8);
        *(bf16x8*)&As[ar * 40 + ah * 16]     = av0;
        *(bf16x8*)&As[ar * 40 + ah * 16 + 8] = av1;
        bf16x8 bv = *(const bf16x8*)(Wt + (size_t)(n0 + bn) * 192 + k0 + bq * 8);
        *(bf16x8*)&Bs[bn * 40 + bq * 8] = bv;
        __syncthreads();
        bf16x8 b0 = *(bf16x8*)&Bs[(wn * 32 + lr) * 40 + lk * 8];
        bf16x8 b1 = *(bf16x8*)&Bs[(wn * 32 + 16 + lr) * 40 + lk * 8];
#pragma unroll
        for (int fm = 0; fm < 4; ++fm) {
            bf16x8 af = *(bf16x8*)&As[(wm * 64 + fm * 16 + lr) * 40 + lk * 8];
            acc[fm][0] = __builtin_amdgcn_mfma_f32_16x16x32_bf16(af, b0, acc[fm][0], 0, 0, 0);
            acc[fm][1] = __builtin_amdgcn_mfma_f32_16x16x32_bf16(af, b1, acc[fm][1], 0, 0, 0);
        }
    }
#pragma unroll
    for (int fm = 0; fm < 4; ++fm)
#pragma unroll
    for (int fn = 0; fn < 2; ++fn) {
        int gn = n0 + wn * 32 + fn * 16 + lr;
        float bias = cb[gn];
#pragma unroll
        for (int r = 0; r < 4; ++r) {
            int gm = m0 + wm * 64 + fm * 16 + lk * 4 + r;
            float v = acc[fm][fn][r] + bias;
            if constexpr (MODE == 0) {
                if (gn < 192) Oa[(size_t)gm * 192 + gn] = f2bf(silu_f(v));
                else          Ob[(size_t)gm * 192 + gn - 192] = f2bf(v);
            } else if constexpr (MODE == 1) {
                float e = (v > 0.f) ? (v + 1.f) : expf(v);
                if (gn < 192) Oa[(size_t)gm * 192 + gn] = f2bf(e);
                else          Ob[(size_t)gm * 192 + gn - 192] = f2bf(e);
            } else {
                Ofp[(size_t)gm * 192 + gn] = v + Xres[(size_t)gm * 192 + gn];
            }
        }
    }
}

// ---------------- depthwise 3x3 (+optional silu), bf16 in/out ----------------
template <bool DO_SILU>
__global__ __launch_bounds__(192) void k_dwc(const ushort* __restrict__ in,
                                             const float* __restrict__ w,
                                             const float* __restrict__ bias,
                                             ushort* __restrict__ out)
{
    int pos = blockIdx.x;
    int c   = threadIdx.x;
    int b   = pos / L_;
    int rem = pos - b * L_;
    int y   = rem / Ww;
    int x   = rem - y * Ww;
    float acc = bias[c];
#pragma unroll
    for (int dy = -1; dy <= 1; ++dy) {
        int yy = y + dy;
        if ((unsigned)yy >= Hh) continue;
#pragma unroll
        for (int dx = -1; dx <= 1; ++dx) {
            int xx = x + dx;
            if ((unsigned)xx >= Ww) continue;
            acc += bf2f(in[((size_t)(b * L_ + yy * Ww + xx)) * C_ + c]) *
                   w[((dy + 1) * 3 + (dx + 1)) * C_ + c];
        }
    }
    if (DO_SILU) acc = silu_f(acc);
    out[(size_t)pos * C_ + c] = f2bf(acc);
}

// ---------------- kv = k^T v / L, kmean: one block per (b,h), no atomics ----------------
__global__ __launch_bounds__(256) void k_kv(const ushort* __restrict__ kbuf,
                                            const ushort* __restrict__ vbuf,
                                            float* __restrict__ kv,
                                            float* __restrict__ ksum)
{
    __shared__ __align__(16) float Ks[16][32];
    __shared__ __align__(16) float Vs[16][32];
    int bh = blockIdx.x;          // 0..95
    int b = bh / NH, h = bh % NH;
    int t = threadIdx.x;
    int d = t >> 3, e0 = (t & 7) << 2;
    float a0 = 0, a1 = 0, a2 = 0, a3 = 0, ks = 0;
    int lr = t & 127, rr = lr >> 3, c4 = (lr & 7) << 2;
    for (int l = 0; l < L_; l += 16) {
        __syncthreads();
        size_t base = ((size_t)(b * L_ + l + rr)) * C_ + h * HD + c4;
        if (t < 128) {
            ushort4 u = *(const ushort4*)(kbuf + base);
            Ks[rr][c4] = bf2f(u.x); Ks[rr][c4 + 1] = bf2f(u.y);
            Ks[rr][c4 + 2] = bf2f(u.z); Ks[rr][c4 + 3] = bf2f(u.w);
        } else {
            ushort4 u = *(const ushort4*)(vbuf + base);
            Vs[rr][c4] = bf2f(u.x); Vs[rr][c4 + 1] = bf2f(u.y);
            Vs[rr][c4 + 2] = bf2f(u.z); Vs[rr][c4 + 3] = bf2f(u.w);
        }
        __syncthreads();
#pragma unroll
        for (int r = 0; r < 16; ++r) {
            float kd = Ks[r][d];
            a0 += kd * Vs[r][e0]; a1 += kd * Vs[r][e0 + 1];
            a2 += kd * Vs[r][e0 + 2]; a3 += kd * Vs[r][e0 + 3];
            if (e0 == 0) ks += kd;
        }
    }
    const float invL = 1.f / (float)L_;
    float* kvp = kv + (size_t)bh * HD * HD + d * HD + e0;
    kvp[0] = a0 * invL; kvp[1] = a1 * invL;
    kvp[2] = a2 * invL; kvp[3] = a3 * invL;
    if (e0 == 0) ksum[bh * HD + d] = ks * invL;
}

// ---------------- attention: att=(q@kv)*z, + lepe, * act, MFMA ----------------
__global__ __launch_bounds__(256) void k_attmm(
    const ushort* __restrict__ q,    // [BL][192] bf16
    const float*  __restrict__ kv,   // [96][32][32] fp32
    const float*  __restrict__ km,   // [96][32] fp32
    const ushort* __restrict__ lepe, // [BL][192] bf16
    const ushort* __restrict__ act,  // [BL][192] bf16
    ushort* __restrict__ outp)       // attres [BL][192] bf16
{
    __shared__ __align__(16) ushort Bs[6][2][16][40];
    __shared__ __align__(16) ushort As[64 * 40];
    __shared__ float  ps[64][4];
    __shared__ float  kms[192];
    const int t = threadIdx.x;
    const int tok0 = blockIdx.x * 64;
    const int b = tok0 / L_;
    const int l = t & 63, w = t >> 6;
    const int lr = l & 15, lk = l >> 4;

    const float* kvg = kv + (size_t)b * NH * HD * HD;
    for (int i = t; i < NH * HD * HD; i += 256) {
        int h = i >> 10, k = (i >> 5) & 31, cp = i & 31;
        Bs[h][cp >> 4][cp & 15][k] = f2bf(kvg[i]);
    }
    if (t < 192) kms[t] = km[b * 192 + t];

    const int sr = t >> 2, sq = t & 3;
    for (int h = 0; h < NH; ++h) {
        __syncthreads();
        {
            const ushort* src = q + (size_t)(tok0 + sr) * 192 + h * 32 + sq * 8;
            bf16x8 v = *(const bf16x8*)src;
            *(bf16x8*)&As[sr * 40 + sq * 8] = v;
            float p = 0.f;
#pragma unroll
            for (int j = 0; j < 8; ++j)
                p += bf2f((ushort)v[j]) * kms[h * 32 + sq * 8 + j];
            ps[sr][sq] = p;
        }
        __syncthreads();
        bf16x8 af = *(bf16x8*)&As[(w * 16 + lr) * 40 + lk * 8];
        bf16x8 b0 = *(bf16x8*)&Bs[h][0][lr][lk * 8];
        bf16x8 b1 = *(bf16x8*)&Bs[h][1][lr][lk * 8];
        f32x4 z4 = {};
        f32x4 acc0 = __builtin_amdgcn_mfma_f32_16x16x32_bf16(af, b0, z4, 0, 0, 0);
        f32x4 acc1 = __builtin_amdgcn_mfma_f32_16x16x32_bf16(af, b1, z4, 0, 0, 0);
        float zr[4];
#pragma unroll
        for (int r = 0; r < 4; ++r) {
            int row = w * 16 + lk * 4 + r;
            zr[r] = 1.f / (ps[row][0] + ps[row][1] + ps[row][2] + ps[row][3] + 1e-6f);
        }
#pragma unroll
        for (int cf = 0; cf < 2; ++cf) {
            f32x4 a = cf ? acc1 : acc0;
#pragma unroll
            for (int r = 0; r < 4; ++r) {
                int row = w * 16 + lk * 4 + r;
                size_t tok = (size_t)(tok0 + row);
                int c = h * 32 + cf * 16 + lr;
                float av = a[r] * zr[r];
                float o = (av + bf2f(lepe[tok * 192 + c])) * bf2f(act[tok * 192 + c]);
                outp[tok * 192 + c] = f2bf(o);
            }
        }
    }
}

extern "C" void kernel_launch(void* const* d_in, const int* in_sizes, int n_in,
                              void* d_out, int out_size, void* d_ws, size_t ws_size,
                              hipStream_t stream)
{
    const float* x      = (const float*)d_in[0];
    const float* norm_g = (const float*)d_in[1];
    const float* norm_b = (const float*)d_in[2];
    const float* in_w   = (const float*)d_in[3];
    const float* in_b   = (const float*)d_in[4];
    const float* act_w  = (const float*)d_in[5];
    const float* act_b  = (const float*)d_in[6];
    const float* dwc_w  = (const float*)d_in[7];
    const float* dwc_b  = (const float*)d_in[8];
    const float* qk_w   = (const float*)d_in[9];
    const float* qk_b   = (const float*)d_in[10];
    const float* lepe_w = (const float*)d_in[11];
    const float* lepe_b = (const float*)d_in[12];
    const float* out_w  = (const float*)d_in[13];
    const float* out_b  = (const float*)d_in[14];
    float* out = (float*)d_out;

    const size_t SZ = (size_t)BL * C_;
    ushort* xn    = (ushort*)d_ws;        // xn, later attres
    ushort* actb  = xn + SZ;
    ushort* h0    = actb + SZ;            // h0, later lepe
    ushort* hbuf  = h0 + SZ;
    ushort* qb    = hbuf + SZ;
    ushort* kb    = qb + SZ;
    float*  kvb   = (float*)(kb + SZ);
    float*  kmean = kvb + 96 * HD * HD;
    float*  cb0   = kmean + 96 * HD;
    ushort* wcat  = (ushort*)(cb0 + 384);
    ushort* qkt   = wcat + 384 * 192;
    ushort* outt  = qkt + 384 * 192;

    k_prep<<<960, 192, 0, stream>>>(act_w, in_w, qk_w, out_w, act_b, in_b,
                                    wcat, qkt, outt, cb0);
    k_ln<<<BL / 4, 256, 0, stream>>>(x, norm_g, norm_b, xn);
    dim3 g1(BL / 128, 6);
    k_mm<0><<<g1, 256, 0, stream>>>(xn, wcat, cb0, actb, h0, nullptr, nullptr);
    k_dwc<true><<<BL, 192, 0, stream>>>(h0, dwc_w, dwc_b, hbuf);
    k_mm<1><<<g1, 256, 0, stream>>>(hbuf, qkt, qk_b, qb, kb, nullptr, nullptr);
    k_kv<<<96, 256, 0, stream>>>(kb, hbuf, kvb, kmean);
    k_dwc<false><<<BL, 192, 0, stream>>>(hbuf, lepe_w, lepe_b, h0);  // lepe -> h0
    k_attmm<<<BL / 64, 256, 0, stream>>>(qb, kvb, kmean, h0, actb, xn);
    dim3 g3(BL / 128, 3);
    k_mm<2><<<g3, 256, 0, stream>>>(xn, outt, out_b, nullptr, nullptr, x, out);
}

// Round 9
// 355.037 us; speedup vs baseline: 1.8333x; 1.2826x over previous
//
#include <hip/hip_runtime.h>
#include <hip/hip_bf16.h>
#include <math.h>

#define B_  16
#define Hh  56
#define Ww  56
#define L_  3136
#define C_  192
#define NH  6
#define HD  32
#define BL  50176   // B_*L_

typedef short bf16x8 __attribute__((ext_vector_type(8)));
typedef float f32x4  __attribute__((ext_vector_type(4)));

__device__ __forceinline__ float silu_f(float v) { return v / (1.f + expf(-v)); }
__device__ __forceinline__ float bf2f(ushort u) { union { uint i; float f; } v; v.i = (uint)u << 16; return v.f; }
__device__ __forceinline__ ushort f2bf(float f) { __hip_bfloat16 h = __float2bfloat16(f); return *reinterpret_cast<ushort*>(&h); }

// ---------------- weight prep: transpose + bf16 cast ----------------
__global__ __launch_bounds__(192) void k_prep(
    const float* __restrict__ act_w, const float* __restrict__ in_w,
    const float* __restrict__ qk_w,  const float* __restrict__ out_w,
    const float* __restrict__ act_b, const float* __restrict__ in_b,
    ushort* __restrict__ wcat, ushort* __restrict__ qkt,
    ushort* __restrict__ outt, float* __restrict__ cb0)
{
    int n = blockIdx.x, k = threadIdx.x;
    if (n < 384) {
        float v = (n < 192) ? act_w[k * 192 + n] : in_w[k * 192 + (n - 192)];
        wcat[n * 192 + k] = f2bf(v);
        if (k == 0) cb0[n] = (n < 192) ? act_b[n] : in_b[n - 192];
    } else if (n < 768) {
        int nn = n - 384;
        qkt[nn * 192 + k] = f2bf(qk_w[k * 384 + nn]);
    } else {
        int nn = n - 768;
        outt[nn * 192 + k] = f2bf(out_w[k * 192 + nn]);
    }
}

// ---------------- LayerNorm -> bf16 ----------------
__global__ __launch_bounds__(256) void k_ln(const float* __restrict__ x,
                                            const float* __restrict__ g,
                                            const float* __restrict__ bt,
                                            ushort* __restrict__ xn)
{
    int token = blockIdx.x * 4 + (threadIdx.x >> 6);
    int lane  = threadIdx.x & 63;
    const float* xr = x + (size_t)token * C_;
    float v0 = xr[lane], v1 = xr[lane + 64], v2 = xr[lane + 128];
    float s  = v0 + v1 + v2;
    float sq = v0 * v0 + v1 * v1 + v2 * v2;
#pragma unroll
    for (int off = 32; off > 0; off >>= 1) {
        s  += __shfl_xor(s, off);
        sq += __shfl_xor(sq, off);
    }
    float mu  = s * (1.f / C_);
    float var = sq * (1.f / C_) - mu * mu;
    float rs  = rsqrtf(var + 1e-5f);
    ushort* o = xn + (size_t)token * C_;
    o[lane]       = f2bf((v0 - mu) * rs * g[lane]       + bt[lane]);
    o[lane + 64]  = f2bf((v1 - mu) * rs * g[lane + 64]  + bt[lane + 64]);
    o[lane + 128] = f2bf((v2 - mu) * rs * g[lane + 128] + bt[lane + 128]);
}

// ---------------- MFMA GEMM: [BL,192] x Wt[NT,192]^T, 128x64 tile ----------------
template <int MODE>
__global__ __launch_bounds__(256) void k_mm(
    const ushort* __restrict__ A, const ushort* __restrict__ Wt,
    const float* __restrict__ cb,
    ushort* __restrict__ Oa, ushort* __restrict__ Ob,
    const float* __restrict__ Xres, float* __restrict__ Ofp)
{
    __shared__ __align__(16) ushort As[128 * 40];
    __shared__ __align__(16) ushort Bs[64 * 40];
    const int t = threadIdx.x;
    const int m0 = blockIdx.x * 128, n0 = blockIdx.y * 64;
    const int l = t & 63, w = t >> 6;
    const int wm = w & 1, wn = w >> 1;
    const int lr = l & 15, lk = l >> 4;
    const int ar = t >> 1, ah = t & 1;
    const int bn = t >> 2, bq = t & 3;

    f32x4 acc[4][2] = {};

    for (int k0 = 0; k0 < 192; k0 += 32) {
        if (k0) __syncthreads();
        const ushort* as = A + (size_t)(m0 + ar) * 192 + k0 + ah * 16;
        bf16x8 av0 = *(const bf16x8*)as;
        bf16x8 av1 = *(const bf16x8*)(as + 8);
        *(bf16x8*)&As[ar * 40 + ah * 16]     = av0;
        *(bf16x8*)&As[ar * 40 + ah * 16 + 8] = av1;
        bf16x8 bv = *(const bf16x8*)(Wt + (size_t)(n0 + bn) * 192 + k0 + bq * 8);
        *(bf16x8*)&Bs[bn * 40 + bq * 8] = bv;
        __syncthreads();
        bf16x8 b0 = *(bf16x8*)&Bs[(wn * 32 + lr) * 40 + lk * 8];
        bf16x8 b1 = *(bf16x8*)&Bs[(wn * 32 + 16 + lr) * 40 + lk * 8];
#pragma unroll
        for (int fm = 0; fm < 4; ++fm) {
            bf16x8 af = *(bf16x8*)&As[(wm * 64 + fm * 16 + lr) * 40 + lk * 8];
            acc[fm][0] = __builtin_amdgcn_mfma_f32_16x16x32_bf16(af, b0, acc[fm][0], 0, 0, 0);
            acc[fm][1] = __builtin_amdgcn_mfma_f32_16x16x32_bf16(af, b1, acc[fm][1], 0, 0, 0);
        }
    }
#pragma unroll
    for (int fm = 0; fm < 4; ++fm)
#pragma unroll
    for (int fn = 0; fn < 2; ++fn) {
        int gn = n0 + wn * 32 + fn * 16 + lr;
        float bias = cb[gn];
#pragma unroll
        for (int r = 0; r < 4; ++r) {
            int gm = m0 + wm * 64 + fm * 16 + lk * 4 + r;
            float v = acc[fm][fn][r] + bias;
            if constexpr (MODE == 0) {
                if (gn < 192) Oa[(size_t)gm * 192 + gn] = f2bf(silu_f(v));
                else          Ob[(size_t)gm * 192 + gn - 192] = f2bf(v);
            } else if constexpr (MODE == 1) {
                float e = (v > 0.f) ? (v + 1.f) : expf(v);
                if (gn < 192) Oa[(size_t)gm * 192 + gn] = f2bf(e);
                else          Ob[(size_t)gm * 192 + gn - 192] = f2bf(e);
            } else {
                Ofp[(size_t)gm * 192 + gn] = v + Xres[(size_t)gm * 192 + gn];
            }
        }
    }
}

// ---------------- depthwise 3x3 (+optional silu), bf16 in/out ----------------
template <bool DO_SILU>
__global__ __launch_bounds__(192) void k_dwc(const ushort* __restrict__ in,
                                             const float* __restrict__ w,
                                             const float* __restrict__ bias,
                                             ushort* __restrict__ out)
{
    int pos = blockIdx.x;
    int c   = threadIdx.x;
    int b   = pos / L_;
    int rem = pos - b * L_;
    int y   = rem / Ww;
    int x   = rem - y * Ww;
    float acc = bias[c];
#pragma unroll
    for (int dy = -1; dy <= 1; ++dy) {
        int yy = y + dy;
        if ((unsigned)yy >= Hh) continue;
#pragma unroll
        for (int dx = -1; dx <= 1; ++dx) {
            int xx = x + dx;
            if ((unsigned)xx >= Ww) continue;
            acc += bf2f(in[((size_t)(b * L_ + yy * Ww + xx)) * C_ + c]) *
                   w[((dy + 1) * 3 + (dx + 1)) * C_ + c];
        }
    }
    if (DO_SILU) acc = silu_f(acc);
    out[(size_t)pos * C_ + c] = f2bf(acc);
}

// ---------------- kv stage 1: partial k^T v over 112-row chunks ----------------
// grid (96, 28); partial[bh*28+chunk] = [32*32 kv | 32 ksum] floats
__global__ __launch_bounds__(256) void k_kv1(const ushort* __restrict__ kbuf,
                                             const ushort* __restrict__ vbuf,
                                             float* __restrict__ part)
{
    __shared__ __align__(16) float Ks[16][32];
    __shared__ __align__(16) float Vs[16][32];
    int bh = blockIdx.x, chunk = blockIdx.y;
    int b = bh / NH, h = bh % NH;
    int t = threadIdx.x;
    int l0 = chunk * 112;
    int d = t >> 3, e0 = (t & 7) << 2;
    float a0 = 0, a1 = 0, a2 = 0, a3 = 0, ks = 0;
    int lr = t & 127, rr = lr >> 3, c4 = (lr & 7) << 2;
    for (int l = l0; l < l0 + 112; l += 16) {
        __syncthreads();
        size_t base = ((size_t)(b * L_ + l + rr)) * C_ + h * HD + c4;
        if (t < 128) {
            ushort4 u = *(const ushort4*)(kbuf + base);
            Ks[rr][c4] = bf2f(u.x); Ks[rr][c4 + 1] = bf2f(u.y);
            Ks[rr][c4 + 2] = bf2f(u.z); Ks[rr][c4 + 3] = bf2f(u.w);
        } else {
            ushort4 u = *(const ushort4*)(vbuf + base);
            Vs[rr][c4] = bf2f(u.x); Vs[rr][c4 + 1] = bf2f(u.y);
            Vs[rr][c4 + 2] = bf2f(u.z); Vs[rr][c4 + 3] = bf2f(u.w);
        }
        __syncthreads();
#pragma unroll
        for (int r = 0; r < 16; ++r) {
            float kd = Ks[r][d];
            a0 += kd * Vs[r][e0]; a1 += kd * Vs[r][e0 + 1];
            a2 += kd * Vs[r][e0 + 2]; a3 += kd * Vs[r][e0 + 3];
            if (e0 == 0) ks += kd;
        }
    }
    float* p = part + (size_t)(bh * 28 + chunk) * 1056;
    p[d * 32 + e0]     = a0;
    p[d * 32 + e0 + 1] = a1;
    p[d * 32 + e0 + 2] = a2;
    p[d * 32 + e0 + 3] = a3;
    if (e0 == 0) p[1024 + d] = ks;
}

// ---------------- kv stage 2: reduce 28 partials, scale by 1/L ----------------
__global__ __launch_bounds__(256) void k_kv2(const float* __restrict__ part,
                                             float* __restrict__ kv,
                                             float* __restrict__ ksum)
{
    int bh = blockIdx.x, t = threadIdx.x;
    const float invL = 1.f / (float)L_;
    const float* pb = part + (size_t)bh * 28 * 1056;
#pragma unroll
    for (int j = 0; j < 4; ++j) {
        int e = t + j * 256;
        float s = 0.f;
        for (int c = 0; c < 28; ++c) s += pb[c * 1056 + e];
        kv[(size_t)bh * 1024 + e] = s * invL;
    }
    if (t < 32) {
        float s = 0.f;
        for (int c = 0; c < 28; ++c) s += pb[c * 1056 + 1024 + t];
        ksum[bh * 32 + t] = s * invL;
    }
}

// ---------------- attention: att=(q@kv)*z, + lepe, * act, MFMA ----------------
__global__ __launch_bounds__(256) void k_attmm(
    const ushort* __restrict__ q,    // [BL][192] bf16
    const float*  __restrict__ kv,   // [96][32][32] fp32
    const float*  __restrict__ km,   // [96][32] fp32
    const ushort* __restrict__ lepe, // [BL][192] bf16
    const ushort* __restrict__ act,  // [BL][192] bf16
    ushort* __restrict__ outp)       // attres [BL][192] bf16
{
    __shared__ __align__(16) ushort Bs[6][2][16][40];
    __shared__ __align__(16) ushort As[64 * 40];
    __shared__ float  ps[64][4];
    __shared__ float  kms[192];
    const int t = threadIdx.x;
    const int tok0 = blockIdx.x * 64;
    const int b = tok0 / L_;
    const int l = t & 63, w = t >> 6;
    const int lr = l & 15, lk = l >> 4;

    const float* kvg = kv + (size_t)b * NH * HD * HD;
    for (int i = t; i < NH * HD * HD; i += 256) {
        int h = i >> 10, k = (i >> 5) & 31, cp = i & 31;
        Bs[h][cp >> 4][cp & 15][k] = f2bf(kvg[i]);
    }
    if (t < 192) kms[t] = km[b * 192 + t];

    const int sr = t >> 2, sq = t & 3;
    for (int h = 0; h < NH; ++h) {
        __syncthreads();
        {
            const ushort* src = q + (size_t)(tok0 + sr) * 192 + h * 32 + sq * 8;
            bf16x8 v = *(const bf16x8*)src;
            *(bf16x8*)&As[sr * 40 + sq * 8] = v;
            float p = 0.f;
#pragma unroll
            for (int j = 0; j < 8; ++j)
                p += bf2f((ushort)v[j]) * kms[h * 32 + sq * 8 + j];
            ps[sr][sq] = p;
        }
        __syncthreads();
        bf16x8 af = *(bf16x8*)&As[(w * 16 + lr) * 40 + lk * 8];
        bf16x8 b0 = *(bf16x8*)&Bs[h][0][lr][lk * 8];
        bf16x8 b1 = *(bf16x8*)&Bs[h][1][lr][lk * 8];
        f32x4 z4 = {};
        f32x4 acc0 = __builtin_amdgcn_mfma_f32_16x16x32_bf16(af, b0, z4, 0, 0, 0);
        f32x4 acc1 = __builtin_amdgcn_mfma_f32_16x16x32_bf16(af, b1, z4, 0, 0, 0);
        float zr[4];
#pragma unroll
        for (int r = 0; r < 4; ++r) {
            int row = w * 16 + lk * 4 + r;
            zr[r] = 1.f / (ps[row][0] + ps[row][1] + ps[row][2] + ps[row][3] + 1e-6f);
        }
#pragma unroll
        for (int cf = 0; cf < 2; ++cf) {
            f32x4 a = cf ? acc1 : acc0;
#pragma unroll
            for (int r = 0; r < 4; ++r) {
                int row = w * 16 + lk * 4 + r;
                size_t tok = (size_t)(tok0 + row);
                int c = h * 32 + cf * 16 + lr;
                float av = a[r] * zr[r];
                float o = (av + bf2f(lepe[tok * 192 + c])) * bf2f(act[tok * 192 + c]);
                outp[tok * 192 + c] = f2bf(o);
            }
        }
    }
}

extern "C" void kernel_launch(void* const* d_in, const int* in_sizes, int n_in,
                              void* d_out, int out_size, void* d_ws, size_t ws_size,
                              hipStream_t stream)
{
    const float* x      = (const float*)d_in[0];
    const float* norm_g = (const float*)d_in[1];
    const float* norm_b = (const float*)d_in[2];
    const float* in_w   = (const float*)d_in[3];
    const float* in_b   = (const float*)d_in[4];
    const float* act_w  = (const float*)d_in[5];
    const float* act_b  = (const float*)d_in[6];
    const float* dwc_w  = (const float*)d_in[7];
    const float* dwc_b  = (const float*)d_in[8];
    const float* qk_w   = (const float*)d_in[9];
    const float* qk_b   = (const float*)d_in[10];
    const float* lepe_w = (const float*)d_in[11];
    const float* lepe_b = (const float*)d_in[12];
    const float* out_w  = (const float*)d_in[13];
    const float* out_b  = (const float*)d_in[14];
    float* out = (float*)d_out;

    const size_t SZ = (size_t)BL * C_;
    ushort* xn    = (ushort*)d_ws;        // xn, later attres
    ushort* actb  = xn + SZ;
    ushort* h0    = actb + SZ;            // h0, later lepe
    ushort* hbuf  = h0 + SZ;
    ushort* qb    = hbuf + SZ;
    ushort* kb    = qb + SZ;
    float*  kvb   = (float*)(kb + SZ);
    float*  kmean = kvb + 96 * HD * HD;
    float*  cb0   = kmean + 96 * HD;
    ushort* wcat  = (ushort*)(cb0 + 384);
    ushort* qkt   = wcat + 384 * 192;
    ushort* outt  = qkt + 384 * 192;
    float*  part  = (float*)(outt + 192 * 192);  // DEDICATED region, no aliasing

    k_prep<<<960, 192, 0, stream>>>(act_w, in_w, qk_w, out_w, act_b, in_b,
                                    wcat, qkt, outt, cb0);
    k_ln<<<BL / 4, 256, 0, stream>>>(x, norm_g, norm_b, xn);
    dim3 g1(BL / 128, 6);
    k_mm<0><<<g1, 256, 0, stream>>>(xn, wcat, cb0, actb, h0, nullptr, nullptr);
    k_dwc<true><<<BL, 192, 0, stream>>>(h0, dwc_w, dwc_b, hbuf);
    k_mm<1><<<g1, 256, 0, stream>>>(hbuf, qkt, qk_b, qb, kb, nullptr, nullptr);
    dim3 g2(96, 28);
    k_kv1<<<g2, 256, 0, stream>>>(kb, hbuf, part);
    k_kv2<<<96, 256, 0, stream>>>(part, kvb, kmean);
    k_dwc<false><<<BL, 192, 0, stream>>>(hbuf, lepe_w, lepe_b, h0);  // lepe -> h0
    k_attmm<<<BL / 64, 256, 0, stream>>>(qb, kvb, kmean, h0, actb, xn);
    dim3 g3(BL / 128, 3);
    k_mm<2><<<g3, 256, 0, stream>>>(xn, outt, out_b, nullptr, nullptr, x, out);
}

// Round 10
// 284.439 us; speedup vs baseline: 2.2883x; 1.2482x over previous
//
#include <hip/hip_runtime.h>
#include <hip/hip_bf16.h>
#include <math.h>

#define B_  16
#define Hh  56
#define Ww  56
#define L_  3136
#define C_  192
#define NH  6
#define HD  32
#define BL  50176   // B_*L_

typedef short bf16x8 __attribute__((ext_vector_type(8)));
typedef float f32x4  __attribute__((ext_vector_type(4)));

__device__ __forceinline__ float silu_f(float v) { return v / (1.f + expf(-v)); }
__device__ __forceinline__ float bf2f(ushort u) { union { uint i; float f; } v; v.i = (uint)u << 16; return v.f; }
__device__ __forceinline__ ushort f2bf(float f) { __hip_bfloat16 h = __float2bfloat16(f); return *reinterpret_cast<ushort*>(&h); }

// ---------------- weight prep: transpose + bf16 cast ----------------
__global__ __launch_bounds__(192) void k_prep(
    const float* __restrict__ act_w, const float* __restrict__ in_w,
    const float* __restrict__ qk_w,  const float* __restrict__ out_w,
    const float* __restrict__ act_b, const float* __restrict__ in_b,
    ushort* __restrict__ wcat, ushort* __restrict__ qkt,
    ushort* __restrict__ outt, float* __restrict__ cb0)
{
    int n = blockIdx.x, k = threadIdx.x;
    if (n < 384) {
        float v = (n < 192) ? act_w[k * 192 + n] : in_w[k * 192 + (n - 192)];
        wcat[n * 192 + k] = f2bf(v);
        if (k == 0) cb0[n] = (n < 192) ? act_b[n] : in_b[n - 192];
    } else if (n < 768) {
        int nn = n - 384;
        qkt[nn * 192 + k] = f2bf(qk_w[k * 384 + nn]);
    } else {
        int nn = n - 768;
        outt[nn * 192 + k] = f2bf(out_w[k * 192 + nn]);
    }
}

// ---------------- LayerNorm -> bf16 ----------------
__global__ __launch_bounds__(256) void k_ln(const float* __restrict__ x,
                                            const float* __restrict__ g,
                                            const float* __restrict__ bt,
                                            ushort* __restrict__ xn)
{
    int token = blockIdx.x * 4 + (threadIdx.x >> 6);
    int lane  = threadIdx.x & 63;
    const float* xr = x + (size_t)token * C_;
    float v0 = xr[lane], v1 = xr[lane + 64], v2 = xr[lane + 128];
    float s  = v0 + v1 + v2;
    float sq = v0 * v0 + v1 * v1 + v2 * v2;
#pragma unroll
    for (int off = 32; off > 0; off >>= 1) {
        s  += __shfl_xor(s, off);
        sq += __shfl_xor(sq, off);
    }
    float mu  = s * (1.f / C_);
    float var = sq * (1.f / C_) - mu * mu;
    float rs  = rsqrtf(var + 1e-5f);
    ushort* o = xn + (size_t)token * C_;
    o[lane]       = f2bf((v0 - mu) * rs * g[lane]       + bt[lane]);
    o[lane + 64]  = f2bf((v1 - mu) * rs * g[lane + 64]  + bt[lane + 64]);
    o[lane + 128] = f2bf((v2 - mu) * rs * g[lane + 128] + bt[lane + 128]);
}

// ---------------- MFMA GEMM: [BL,192] x Wt[NT,192]^T, 128x64 tile ----------------
template <int MODE>
__global__ __launch_bounds__(256) void k_mm(
    const ushort* __restrict__ A, const ushort* __restrict__ Wt,
    const float* __restrict__ cb,
    ushort* __restrict__ Oa, ushort* __restrict__ Ob,
    const float* __restrict__ Xres, float* __restrict__ Ofp)
{
    __shared__ __align__(16) ushort As[128 * 40];
    __shared__ __align__(16) ushort Bs[64 * 40];
    const int t = threadIdx.x;
    const int m0 = blockIdx.x * 128, n0 = blockIdx.y * 64;
    const int l = t & 63, w = t >> 6;
    const int wm = w & 1, wn = w >> 1;
    const int lr = l & 15, lk = l >> 4;
    const int ar = t >> 1, ah = t & 1;
    const int bn = t >> 2, bq = t & 3;

    f32x4 acc[4][2] = {};

    for (int k0 = 0; k0 < 192; k0 += 32) {
        if (k0) __syncthreads();
        const ushort* as = A + (size_t)(m0 + ar) * 192 + k0 + ah * 16;
        bf16x8 av0 = *(const bf16x8*)as;
        bf16x8 av1 = *(const bf16x8*)(as + 8);
        *(bf16x8*)&As[ar * 40 + ah * 16]     = av0;
        *(bf16x8*)&As[ar * 40 + ah * 16 + 8] = av1;
        bf16x8 bv = *(const bf16x8*)(Wt + (size_t)(n0 + bn) * 192 + k0 + bq * 8);
        *(bf16x8*)&Bs[bn * 40 + bq * 8] = bv;
        __syncthreads();
        bf16x8 b0 = *(bf16x8*)&Bs[(wn * 32 + lr) * 40 + lk * 8];
        bf16x8 b1 = *(bf16x8*)&Bs[(wn * 32 + 16 + lr) * 40 + lk * 8];
#pragma unroll
        for (int fm = 0; fm < 4; ++fm) {
            bf16x8 af = *(bf16x8*)&As[(wm * 64 + fm * 16 + lr) * 40 + lk * 8];
            acc[fm][0] = __builtin_amdgcn_mfma_f32_16x16x32_bf16(af, b0, acc[fm][0], 0, 0, 0);
            acc[fm][1] = __builtin_amdgcn_mfma_f32_16x16x32_bf16(af, b1, acc[fm][1], 0, 0, 0);
        }
    }
#pragma unroll
    for (int fm = 0; fm < 4; ++fm)
#pragma unroll
    for (int fn = 0; fn < 2; ++fn) {
        int gn = n0 + wn * 32 + fn * 16 + lr;
        float bias = cb[gn];
#pragma unroll
        for (int r = 0; r < 4; ++r) {
            int gm = m0 + wm * 64 + fm * 16 + lk * 4 + r;
            float v = acc[fm][fn][r] + bias;
            if constexpr (MODE == 0) {
                if (gn < 192) Oa[(size_t)gm * 192 + gn] = f2bf(silu_f(v));
                else          Ob[(size_t)gm * 192 + gn - 192] = f2bf(v);
            } else if constexpr (MODE == 1) {
                float e = (v > 0.f) ? (v + 1.f) : expf(v);
                if (gn < 192) Oa[(size_t)gm * 192 + gn] = f2bf(e);
                else          Ob[(size_t)gm * 192 + gn - 192] = f2bf(e);
            } else {
                Ofp[(size_t)gm * 192 + gn] = v + Xres[(size_t)gm * 192 + gn];
            }
        }
    }
}

// ---------------- depthwise 3x3 (+optional silu), 8 ch/thread, 16B loads ----------------
// grid: BL*24/256 = 4704 blocks; thread = (pixel, channel-group-of-8)
template <bool DO_SILU>
__global__ __launch_bounds__(256) void k_dwc(const ushort* __restrict__ in,
                                             const float* __restrict__ w,
                                             const float* __restrict__ bias,
                                             ushort* __restrict__ out)
{
    int idx = blockIdx.x * 256 + threadIdx.x;
    int p   = idx / 24;            // pixel index 0..BL-1
    int cg  = idx - p * 24;        // channel group
    int c0  = cg * 8;
    int b   = p / L_;
    int rem = p - b * L_;
    int y   = rem / Ww;
    int x   = rem - y * Ww;

    // hoist weights (9 taps x 8 ch) and bias into registers
    float wr[9][8];
#pragma unroll
    for (int j = 0; j < 9; ++j) {
        f32x4 wa = *(const f32x4*)(w + j * C_ + c0);
        f32x4 wb = *(const f32x4*)(w + j * C_ + c0 + 4);
        wr[j][0] = wa[0]; wr[j][1] = wa[1]; wr[j][2] = wa[2]; wr[j][3] = wa[3];
        wr[j][4] = wb[0]; wr[j][5] = wb[1]; wr[j][6] = wb[2]; wr[j][7] = wb[3];
    }
    float acc[8];
    {
        f32x4 ba = *(const f32x4*)(bias + c0);
        f32x4 bb = *(const f32x4*)(bias + c0 + 4);
        acc[0] = ba[0]; acc[1] = ba[1]; acc[2] = ba[2]; acc[3] = ba[3];
        acc[4] = bb[0]; acc[5] = bb[1]; acc[6] = bb[2]; acc[7] = bb[3];
    }
    const ushort* base = in + (size_t)p * C_ + c0;
#pragma unroll
    for (int dy = -1; dy <= 1; ++dy) {
        int yy = y + dy;
        if ((unsigned)yy >= Hh) continue;
#pragma unroll
        for (int dx = -1; dx <= 1; ++dx) {
            int xx = x + dx;
            if ((unsigned)xx >= Ww) continue;
            bf16x8 v = *(const bf16x8*)(base + (dy * Ww + dx) * C_);
            const int j = (dy + 1) * 3 + (dx + 1);
#pragma unroll
            for (int e = 0; e < 8; ++e)
                acc[e] += bf2f((ushort)v[e]) * wr[j][e];
        }
    }
    bf16x8 ov;
#pragma unroll
    for (int e = 0; e < 8; ++e) {
        float r = DO_SILU ? silu_f(acc[e]) : acc[e];
        ov[e] = (short)f2bf(r);
    }
    *(bf16x8*)(out + (size_t)p * C_ + c0) = ov;
}

// ---------------- kv stage 1: partial k^T v over 112-row chunks ----------------
// grid (96, 28); partial[bh*28+chunk] = [32*32 kv | 32 ksum] floats
__global__ __launch_bounds__(256) void k_kv1(const ushort* __restrict__ kbuf,
                                             const ushort* __restrict__ vbuf,
                                             float* __restrict__ part)
{
    __shared__ __align__(16) float Ks[16][32];
    __shared__ __align__(16) float Vs[16][32];
    int bh = blockIdx.x, chunk = blockIdx.y;
    int b = bh / NH, h = bh % NH;
    int t = threadIdx.x;
    int l0 = chunk * 112;
    int d = t >> 3, e0 = (t & 7) << 2;
    float a0 = 0, a1 = 0, a2 = 0, a3 = 0, ks = 0;
    int lr = t & 127, rr = lr >> 3, c4 = (lr & 7) << 2;
    for (int l = l0; l < l0 + 112; l += 16) {
        __syncthreads();
        size_t base = ((size_t)(b * L_ + l + rr)) * C_ + h * HD + c4;
        if (t < 128) {
            ushort4 u = *(const ushort4*)(kbuf + base);
            Ks[rr][c4] = bf2f(u.x); Ks[rr][c4 + 1] = bf2f(u.y);
            Ks[rr][c4 + 2] = bf2f(u.z); Ks[rr][c4 + 3] = bf2f(u.w);
        } else {
            ushort4 u = *(const ushort4*)(vbuf + base);
            Vs[rr][c4] = bf2f(u.x); Vs[rr][c4 + 1] = bf2f(u.y);
            Vs[rr][c4 + 2] = bf2f(u.z); Vs[rr][c4 + 3] = bf2f(u.w);
        }
        __syncthreads();
#pragma unroll
        for (int r = 0; r < 16; ++r) {
            float kd = Ks[r][d];
            a0 += kd * Vs[r][e0]; a1 += kd * Vs[r][e0 + 1];
            a2 += kd * Vs[r][e0 + 2]; a3 += kd * Vs[r][e0 + 3];
            if (e0 == 0) ks += kd;
        }
    }
    float* p = part + (size_t)(bh * 28 + chunk) * 1056;
    p[d * 32 + e0]     = a0;
    p[d * 32 + e0 + 1] = a1;
    p[d * 32 + e0 + 2] = a2;
    p[d * 32 + e0 + 3] = a3;
    if (e0 == 0) p[1024 + d] = ks;
}

// ---------------- kv stage 2: reduce 28 partials, scale by 1/L ----------------
__global__ __launch_bounds__(256) void k_kv2(const float* __restrict__ part,
                                             float* __restrict__ kv,
                                             float* __restrict__ ksum)
{
    int bh = blockIdx.x, t = threadIdx.x;
    const float invL = 1.f / (float)L_;
    const float* pb = part + (size_t)bh * 28 * 1056;
#pragma unroll
    for (int j = 0; j < 4; ++j) {
        int e = t + j * 256;
        float s = 0.f;
        for (int c = 0; c < 28; ++c) s += pb[c * 1056 + e];
        kv[(size_t)bh * 1024 + e] = s * invL;
    }
    if (t < 32) {
        float s = 0.f;
        for (int c = 0; c < 28; ++c) s += pb[c * 1056 + 1024 + t];
        ksum[bh * 32 + t] = s * invL;
    }
}

// ---------------- attention: att=(q@kv)*z, + lepe, * act, MFMA ----------------
__global__ __launch_bounds__(256) void k_attmm(
    const ushort* __restrict__ q,    // [BL][192] bf16
    const float*  __restrict__ kv,   // [96][32][32] fp32
    const float*  __restrict__ km,   // [96][32] fp32
    const ushort* __restrict__ lepe, // [BL][192] bf16
    const ushort* __restrict__ act,  // [BL][192] bf16
    ushort* __restrict__ outp)       // attres [BL][192] bf16
{
    __shared__ __align__(16) ushort Bs[6][2][16][40];
    __shared__ __align__(16) ushort As[64 * 40];
    __shared__ float  ps[64][4];
    __shared__ float  kms[192];
    const int t = threadIdx.x;
    const int tok0 = blockIdx.x * 64;
    const int b = tok0 / L_;
    const int l = t & 63, w = t >> 6;
    const int lr = l & 15, lk = l >> 4;

    const float* kvg = kv + (size_t)b * NH * HD * HD;
    for (int i = t; i < NH * HD * HD; i += 256) {
        int h = i >> 10, k = (i >> 5) & 31, cp = i & 31;
        Bs[h][cp >> 4][cp & 15][k] = f2bf(kvg[i]);
    }
    if (t < 192) kms[t] = km[b * 192 + t];

    const int sr = t >> 2, sq = t & 3;
    for (int h = 0; h < NH; ++h) {
        __syncthreads();
        {
            const ushort* src = q + (size_t)(tok0 + sr) * 192 + h * 32 + sq * 8;
            bf16x8 v = *(const bf16x8*)src;
            *(bf16x8*)&As[sr * 40 + sq * 8] = v;
            float p = 0.f;
#pragma unroll
            for (int j = 0; j < 8; ++j)
                p += bf2f((ushort)v[j]) * kms[h * 32 + sq * 8 + j];
            ps[sr][sq] = p;
        }
        __syncthreads();
        bf16x8 af = *(bf16x8*)&As[(w * 16 + lr) * 40 + lk * 8];
        bf16x8 b0 = *(bf16x8*)&Bs[h][0][lr][lk * 8];
        bf16x8 b1 = *(bf16x8*)&Bs[h][1][lr][lk * 8];
        f32x4 z4 = {};
        f32x4 acc0 = __builtin_amdgcn_mfma_f32_16x16x32_bf16(af, b0, z4, 0, 0, 0);
        f32x4 acc1 = __builtin_amdgcn_mfma_f32_16x16x32_bf16(af, b1, z4, 0, 0, 0);
        float zr[4];
#pragma unroll
        for (int r = 0; r < 4; ++r) {
            int row = w * 16 + lk * 4 + r;
            zr[r] = 1.f / (ps[row][0] + ps[row][1] + ps[row][2] + ps[row][3] + 1e-6f);
        }
#pragma unroll
        for (int cf = 0; cf < 2; ++cf) {
            f32x4 a = cf ? acc1 : acc0;
#pragma unroll
            for (int r = 0; r < 4; ++r) {
                int row = w * 16 + lk * 4 + r;
                size_t tok = (size_t)(tok0 + row);
                int c = h * 32 + cf * 16 + lr;
                float av = a[r] * zr[r];
                float o = (av + bf2f(lepe[tok * 192 + c])) * bf2f(act[tok * 192 + c]);
                outp[tok * 192 + c] = f2bf(o);
            }
        }
    }
}

extern "C" void kernel_launch(void* const* d_in, const int* in_sizes, int n_in,
                              void* d_out, int out_size, void* d_ws, size_t ws_size,
                              hipStream_t stream)
{
    const float* x      = (const float*)d_in[0];
    const float* norm_g = (const float*)d_in[1];
    const float* norm_b = (const float*)d_in[2];
    const float* in_w   = (const float*)d_in[3];
    const float* in_b   = (const float*)d_in[4];
    const float* act_w  = (const float*)d_in[5];
    const float* act_b  = (const float*)d_in[6];
    const float* dwc_w  = (const float*)d_in[7];
    const float* dwc_b  = (const float*)d_in[8];
    const float* qk_w   = (const float*)d_in[9];
    const float* qk_b   = (const float*)d_in[10];
    const float* lepe_w = (const float*)d_in[11];
    const float* lepe_b = (const float*)d_in[12];
    const float* out_w  = (const float*)d_in[13];
    const float* out_b  = (const float*)d_in[14];
    float* out = (float*)d_out;

    const size_t SZ = (size_t)BL * C_;
    ushort* xn    = (ushort*)d_ws;        // xn, later attres
    ushort* actb  = xn + SZ;
    ushort* h0    = actb + SZ;            // h0, later lepe
    ushort* hbuf  = h0 + SZ;
    ushort* qb    = hbuf + SZ;
    ushort* kb    = qb + SZ;
    float*  kvb   = (float*)(kb + SZ);
    float*  kmean = kvb + 96 * HD * HD;
    float*  cb0   = kmean + 96 * HD;
    ushort* wcat  = (ushort*)(cb0 + 384);
    ushort* qkt   = wcat + 384 * 192;
    ushort* outt  = qkt + 384 * 192;
    float*  part  = (float*)(outt + 192 * 192);  // DEDICATED region, no aliasing

    k_prep<<<960, 192, 0, stream>>>(act_w, in_w, qk_w, out_w, act_b, in_b,
                                    wcat, qkt, outt, cb0);
    k_ln<<<BL / 4, 256, 0, stream>>>(x, norm_g, norm_b, xn);
    dim3 g1(BL / 128, 6);
    k_mm<0><<<g1, 256, 0, stream>>>(xn, wcat, cb0, actb, h0, nullptr, nullptr);
    k_dwc<true><<<(BL * 24) / 256, 256, 0, stream>>>(h0, dwc_w, dwc_b, hbuf);
    k_mm<1><<<g1, 256, 0, stream>>>(hbuf, qkt, qk_b, qb, kb, nullptr, nullptr);
    dim3 g2(96, 28);
    k_kv1<<<g2, 256, 0, stream>>>(kb, hbuf, part);
    k_kv2<<<96, 256, 0, stream>>>(part, kvb, kmean);
    k_dwc<false><<<(BL * 24) / 256, 256, 0, stream>>>(hbuf, lepe_w, lepe_b, h0);  // lepe -> h0
    k_attmm<<<BL / 64, 256, 0, stream>>>(qb, kvb, kmean, h0, actb, xn);
    dim3 g3(BL / 128, 3);
    k_mm<2><<<g3, 256, 0, stream>>>(xn, outt, out_b, nullptr, nullptr, x, out);
}